// Round 8
// baseline (268.782 us; speedup 1.0000x reference)
//
#include <hip/hip_runtime.h>
#include <stdint.h>

// B=2, T=2048, DIM=1024, H=16, HD=64. Device tensors FLOAT32; internally
// convert to bf16 once, run bf16-MFMA pipeline, final GEMM writes f32.
//
// ws (40MB): xb@0 (8MB), wb@8MB (4x2MB), Kb@16MB [4096,1024],
// VT@24MB [32 bh][64 d][2048 t], Ob@32MB [4096,1024]. Qb (bf16, PRE-SCALED by
// 0.125*log2e) lives in d_out's first 8MB (dead before final GEMM).
//
// GEMM: 128x128 tile, BK=64, 4 waves, DOUBLE-BUFFERED LDS (T3-minimum
// 2-phase: stage k+1 into buf^1, compute buf, one barrier/K-step) so the
// global_load_lds latency hides under the MFMA phase.
// attn: swapped QK^T, two independent q-tile chains/wave, tree reductions,
// peeled diagonal, exp2 domain, defer-max. (unchanged from round 7)

#define T_SEQ 2048
#define QSCALE 0.1803368801111204f   // 0.125 * log2(e)

typedef unsigned short u16;
typedef __attribute__((ext_vector_type(8))) __bf16 bf16x8;   // MFMA A/B frag
typedef __attribute__((ext_vector_type(4))) float  f32x4;    // MFMA C/D frag

#define NEG_BIG (-30000.0f)

__device__ __forceinline__ u16 f2bf(float x) {
    union { float f; unsigned u; } c; c.f = x;
    return (u16)((c.u + 0x7fffu + ((c.u >> 16) & 1u)) >> 16);
}

__device__ __forceinline__ void gload_lds16(const void* g, void* l) {
    __builtin_amdgcn_global_load_lds(
        (const __attribute__((address_space(1))) void*)g,
        (__attribute__((address_space(3))) void*)l, 16, 0, 0);
}

__device__ __forceinline__ void storeC(u16* p, float v)   { *p = f2bf(v); }
__device__ __forceinline__ void storeC(float* p, float v) { *p = v; }

// ---------------------------------------------------------------------------
__global__ __launch_bounds__(256) void cvt_all(
    const float* __restrict__ x,  const float* __restrict__ wq,
    const float* __restrict__ wk, const float* __restrict__ wv,
    const float* __restrict__ wo, u16* __restrict__ xb, u16* __restrict__ wb)
{
    int i = blockIdx.x * 256 + threadIdx.x;        // 0 .. 2097151
    const float* s; u16* d; int off;
    if (i < 1048576) { s = x; d = xb; off = i; }
    else {
        int j = i - 1048576;
        int wsel = j >> 18;
        off = j & 262143;
        s = wsel == 0 ? wq : wsel == 1 ? wk : wsel == 2 ? wv : wo;
        d = wb + (size_t)wsel * 1048576u;
    }
    float4 v = ((const float4*)s)[off];
    ushort4 o;
    o.x = f2bf(v.x); o.y = f2bf(v.y); o.z = f2bf(v.z); o.w = f2bf(v.w);
    ((ushort4*)d)[off] = o;
}

// ---------------------------------------------------------------------------
// GEMM: C[4096][1024] = A @ W^T (bf16, both K-contiguous). 128x128 tile,
// BK=64, 4 waves, DOUBLE-BUFFERED LDS + prefetch-next-tile (2-phase).
// VT_MODE: z==2 writes C transposed per-head into VT[bh][d][t]; z==0 (Q)
// pre-scales output by QSCALE.
// ---------------------------------------------------------------------------
template <typename OutT, bool VT_MODE>
__global__ __launch_bounds__(256) void gemm_bt(
    const u16* __restrict__ A, const u16* __restrict__ Wb,
    OutT* __restrict__ C0, OutT* __restrict__ C1, OutT* __restrict__ C2)
{
    __shared__ __align__(16) char As[2][128 * 128];   // 2 x 16KB
    __shared__ __align__(16) char Bs[2][128 * 128];

    const u16* W = Wb + (size_t)blockIdx.z * 1048576u;
    OutT* Cz = blockIdx.z == 0 ? C0 : (blockIdx.z == 1 ? C1 : C2);

    const int tid = threadIdx.x;
    const int w = tid >> 6, l = tid & 63;
    const int wy = w >> 1, wx = w & 1;
    const int bm = blockIdx.y * 128, bn = blockIdx.x * 128;

    f32x4 acc[4][4];
#pragma unroll
    for (int m = 0; m < 4; m++)
#pragma unroll
        for (int n = 0; n < 4; n++) acc[m][n] = (f32x4){0.f, 0.f, 0.f, 0.f};

    const int lrow = l >> 3, lslot = l & 7;

    // per-wave staging addresses: wave w stages chunks 4w..4w+3 of A and B
    auto stage = [&](int buf, int kt) {
#pragma unroll
        for (int c = 0; c < 4; ++c) {
            int ch = w * 4 + c;
            int row = ch * 8 + lrow;
            gload_lds16((const char*)A + ((size_t)(bm + row) * 1024 + kt * 64) * 2 + lslot * 16,
                        As[buf] + ch * 1024);
            gload_lds16((const char*)W + ((size_t)(bn + row) * 1024 + kt * 64) * 2 + lslot * 16,
                        Bs[buf] + ch * 1024);
        }
    };

    stage(0, 0);
    __syncthreads();                       // drain buf0 loads (vmcnt0 + barrier)

    int cur = 0;
    for (int kt = 0; kt < 16; ++kt) {      // K = 16 * 64
        if (kt < 15) stage(cur ^ 1, kt + 1);   // prefetch next tile (hidden)

#pragma unroll
        for (int kk = 0; kk < 2; ++kk) {
            const int cb = (kk * 32 + (l >> 4) * 8) * 2;
            bf16x8 af[4], bfr[4];
#pragma unroll
            for (int m = 0; m < 4; m++)
                af[m] = *(const bf16x8*)(As[cur] + (wy * 64 + m * 16 + (l & 15)) * 128 + cb);
#pragma unroll
            for (int n = 0; n < 4; n++)
                bfr[n] = *(const bf16x8*)(Bs[cur] + (wx * 64 + n * 16 + (l & 15)) * 128 + cb);
#pragma unroll
            for (int m = 0; m < 4; m++)
#pragma unroll
                for (int n = 0; n < 4; n++)
                    acc[m][n] = __builtin_amdgcn_mfma_f32_16x16x32_bf16(
                        af[m], bfr[n], acc[m][n], 0, 0, 0);
        }
        __syncthreads();                   // drain prefetch + protect buf reuse
        cur ^= 1;
    }

    const bool vtw = VT_MODE && (blockIdx.z == 2);
    const float osc = (VT_MODE && blockIdx.z == 0) ? QSCALE : 1.0f;
#pragma unroll
    for (int m = 0; m < 4; m++) {
        int grow0 = bm + wy * 64 + m * 16 + (l >> 4) * 4;
#pragma unroll
        for (int n = 0; n < 4; n++) {
            int gcol = bn + wx * 64 + n * 16 + (l & 15);
            if (vtw) {
                int bh = (grow0 >> 11) * 16 + (gcol >> 6);
                size_t rowbase = ((size_t)bh * 64 + (gcol & 63)) * T_SEQ + (grow0 & 2047);
#pragma unroll
                for (int r = 0; r < 4; r++)
                    storeC(&Cz[rowbase + r], acc[m][n][r]);
            } else {
#pragma unroll
                for (int r = 0; r < 4; r++)
                    storeC(&Cz[(size_t)(grow0 + r) * 1024 + gcol], acc[m][n][r] * osc);
            }
        }
    }
}

// ---------------------------------------------------------------------------
// softmax step for one chain (tree reductions, defer-max). Lane owns q-row
// qrow_g; its 16 scores are s[nt][r] at k = kbase + nt*16 + g*4 + r.
// ---------------------------------------------------------------------------
__device__ __forceinline__ void online_sm(
    f32x4 (&s)[4], f32x4 (&oacc)[4], float& mrun, float& lrun,
    int qrow_g, int kbase, bool diag, int g, u16 (*__restrict__ Ps)[72], int q16)
{
    if (diag) {
#pragma unroll
        for (int nt = 0; nt < 4; ++nt)
#pragma unroll
            for (int r = 0; r < 4; ++r)
                if (kbase + nt * 16 + g * 4 + r > qrow_g) s[nt][r] = NEG_BIG;
    }
    float a0 = fmaxf(fmaxf(s[0][0], s[0][1]), fmaxf(s[0][2], s[0][3]));
    float a1 = fmaxf(fmaxf(s[1][0], s[1][1]), fmaxf(s[1][2], s[1][3]));
    float a2 = fmaxf(fmaxf(s[2][0], s[2][1]), fmaxf(s[2][2], s[2][3]));
    float a3 = fmaxf(fmaxf(s[3][0], s[3][1]), fmaxf(s[3][2], s[3][3]));
    float pm = fmaxf(fmaxf(a0, a1), fmaxf(a2, a3));
    pm = fmaxf(pm, __shfl_xor(pm, 16));
    pm = fmaxf(pm, __shfl_xor(pm, 32));

    const bool noresc = __all(pm <= mrun + 8.0f);
    const float mnew = noresc ? mrun : fmaxf(mrun, pm);

#pragma unroll
    for (int nt = 0; nt < 4; ++nt)
#pragma unroll
        for (int r = 0; r < 4; ++r)
            s[nt][r] = __builtin_amdgcn_exp2f(s[nt][r] - mnew);

    float b0 = (s[0][0] + s[0][1]) + (s[0][2] + s[0][3]);
    float b1 = (s[1][0] + s[1][1]) + (s[1][2] + s[1][3]);
    float b2 = (s[2][0] + s[2][1]) + (s[2][2] + s[2][3]);
    float b3 = (s[3][0] + s[3][1]) + (s[3][2] + s[3][3]);
    float rs = (b0 + b1) + (b2 + b3);
    rs += __shfl_xor(rs, 16);
    rs += __shfl_xor(rs, 32);

    if (!noresc) {
        float alpha = __builtin_amdgcn_exp2f(mrun - mnew);
        lrun *= alpha;
#pragma unroll
        for (int nt = 0; nt < 4; ++nt)
#pragma unroll
            for (int r = 0; r < 4; ++r) oacc[nt][r] *= alpha;
        mrun = mnew;
    }
    lrun += rs;

#pragma unroll
    for (int nt = 0; nt < 4; ++nt) {
        ushort4 pk;
        pk.x = f2bf(s[nt][0]); pk.y = f2bf(s[nt][1]);
        pk.z = f2bf(s[nt][2]); pk.w = f2bf(s[nt][3]);
        *(ushort4*)(&Ps[q16][nt * 16 + g * 4]) = pk;
    }
}

// ---------------------------------------------------------------------------
// Flash attention, causal, 1 wave/block, TWO 16-row q-tiles per wave
// (q-tiles 2y and 2y+1 — identical kt range, shared K/V loads).
// ---------------------------------------------------------------------------
__global__ __launch_bounds__(64) void attn_fwd(
    const u16* __restrict__ Q, const u16* __restrict__ K,
    const u16* __restrict__ VT, u16* __restrict__ O)
{
    __shared__ __align__(16) u16 PsA[16][72];
    __shared__ __align__(16) u16 PsB[16][72];

    const int bh = blockIdx.x;                     // 0..31
    const int y0 = blockIdx.y;                     // 0..63
    const int y = (y0 & 1) ? (63 - (y0 >> 1)) : (y0 >> 1);   // balance
    const int b = bh >> 4, h = bh & 15;
    const int l = threadIdx.x;
    const int g = l >> 4, q16 = l & 15;
    const size_t base = (size_t)b * T_SEQ * 1024 + h * 64;
    const u16* vtb = VT + (size_t)bh * 64 * T_SEQ;

    const int qgA = y * 32, qgB = qgA + 16;
    const int qrA = qgA + q16, qrB = qgB + q16;
    const int ktmax = (qgA + 31) >> 6;

    const u16* qpA = Q + base + (size_t)qrA * 1024 + g * 8;
    const u16* qpB = Q + base + (size_t)qrB * 1024 + g * 8;
    bf16x8 qfA[2], qfB[2];
    qfA[0] = *(const bf16x8*)(qpA); qfA[1] = *(const bf16x8*)(qpA + 32);
    qfB[0] = *(const bf16x8*)(qpB); qfB[1] = *(const bf16x8*)(qpB + 32);

    f32x4 oaccA[4], oaccB[4];
#pragma unroll
    for (int n = 0; n < 4; n++) {
        oaccA[n] = (f32x4){0.f, 0.f, 0.f, 0.f};
        oaccB[n] = (f32x4){0.f, 0.f, 0.f, 0.f};
    }
    float mA = NEG_BIG, lA = 0.f, mB = NEG_BIG, lB = 0.f;

    auto run_iter = [&](int kt, bool diag) {
        const int kbase = kt * 64;

        bf16x8 kf[2][4], vf[2][4];
#pragma unroll
        for (int kk = 0; kk < 2; ++kk)
#pragma unroll
            for (int nt = 0; nt < 4; ++nt) {
                kf[kk][nt] = *(const bf16x8*)(K + base
                    + (size_t)(kbase + nt * 16 + q16) * 1024 + kk * 32 + g * 8);
                vf[kk][nt] = *(const bf16x8*)(vtb
                    + (size_t)(nt * 16 + q16) * T_SEQ + kbase + kk * 32 + g * 8);
            }

        f32x4 sA[4], sB[4];
#pragma unroll
        for (int n = 0; n < 4; n++) {
            sA[n] = (f32x4){0.f, 0.f, 0.f, 0.f};
            sB[n] = (f32x4){0.f, 0.f, 0.f, 0.f};
        }
#pragma unroll
        for (int kk = 0; kk < 2; ++kk)
#pragma unroll
            for (int nt = 0; nt < 4; ++nt) {
                if (!diag || (kbase + nt * 16 <= qgA + 15))
                    sA[nt] = __builtin_amdgcn_mfma_f32_16x16x32_bf16(
                        kf[kk][nt], qfA[kk], sA[nt], 0, 0, 0);
                if (!diag || (kbase + nt * 16 <= qgB + 15))
                    sB[nt] = __builtin_amdgcn_mfma_f32_16x16x32_bf16(
                        kf[kk][nt], qfB[kk], sB[nt], 0, 0, 0);
            }

        online_sm(sA, oaccA, mA, lA, qrA, kbase, diag, g, PsA, q16);
        online_sm(sB, oaccB, mB, lB, qrB, kbase, diag, g, PsB, q16);

#pragma unroll
        for (int kk = 0; kk < 2; ++kk) {
            bf16x8 pfA = *(const bf16x8*)(&PsA[q16][kk * 32 + g * 8]);
            bf16x8 pfB = *(const bf16x8*)(&PsB[q16][kk * 32 + g * 8]);
            const bool okA = !diag || (kbase + kk * 32 <= qgA + 15);
            const bool okB = !diag || (kbase + kk * 32 <= qgB + 15);
#pragma unroll
            for (int nt = 0; nt < 4; ++nt) {
                if (okA)
                    oaccA[nt] = __builtin_amdgcn_mfma_f32_16x16x32_bf16(
                        vf[kk][nt], pfA, oaccA[nt], 0, 0, 0);
                if (okB)
                    oaccB[nt] = __builtin_amdgcn_mfma_f32_16x16x32_bf16(
                        vf[kk][nt], pfB, oaccB[nt], 0, 0, 0);
            }
        }
    };

    for (int kt = 0; kt < ktmax; ++kt) run_iter(kt, false);
    run_iter(ktmax, true);

    const float riA = __builtin_amdgcn_rcpf(lA);
    const float riB = __builtin_amdgcn_rcpf(lB);
    u16* orowA = O + (size_t)b * T_SEQ * 1024 + (size_t)qrA * 1024 + h * 64;
    u16* orowB = O + (size_t)b * T_SEQ * 1024 + (size_t)qrB * 1024 + h * 64;
#pragma unroll
    for (int nt = 0; nt < 4; ++nt) {
        ushort4 oa, ob;
        oa.x = f2bf(oaccA[nt][0] * riA); oa.y = f2bf(oaccA[nt][1] * riA);
        oa.z = f2bf(oaccA[nt][2] * riA); oa.w = f2bf(oaccA[nt][3] * riA);
        ob.x = f2bf(oaccB[nt][0] * riB); ob.y = f2bf(oaccB[nt][1] * riB);
        ob.z = f2bf(oaccB[nt][2] * riB); ob.w = f2bf(oaccB[nt][3] * riB);
        *(ushort4*)(orowA + nt * 16 + g * 4) = oa;
        *(ushort4*)(orowB + nt * 16 + g * 4) = ob;
    }
}

// ---------------------------------------------------------------------------
extern "C" void kernel_launch(void* const* d_in, const int* in_sizes, int n_in,
                              void* d_out, int out_size, void* d_ws, size_t ws_size,
                              hipStream_t stream)
{
    (void)in_sizes; (void)n_in; (void)out_size; (void)ws_size;
    const float* x  = (const float*)d_in[0];
    const float* wq = (const float*)d_in[1];
    const float* wk = (const float*)d_in[2];
    const float* wv = (const float*)d_in[3];
    const float* wo = (const float*)d_in[4];
    float* out = (float*)d_out;

    char* ws = (char*)d_ws;
    u16* xb = (u16*)(ws);                    // x bf16, 8MB
    u16* wb = (u16*)(ws + (8u << 20));       // wq,wk,wv,wo bf16
    u16* Kb = (u16*)(ws + (16u << 20));      // [4096,1024]
    u16* VT = (u16*)(ws + (24u << 20));      // [32][64][2048] V^T
    u16* Ob = (u16*)(ws + (32u << 20));      // [4096,1024]
    u16* Qb = (u16*)d_out;                   // Q bf16 (pre-scaled) in d_out

    dim3 blk(256);
    cvt_all<<<8192, blk, 0, stream>>>(x, wq, wk, wv, wo, xb, wb);

    // Q (scaled), K row-major; V written transposed into VT
    gemm_bt<u16, true><<<dim3(8, 32, 3), blk, 0, stream>>>(xb, wb, Qb, Kb, VT);
    // causal flash attention: 1-wave blocks, two 16-row q-tiles each
    attn_fwd<<<dim3(32, 64, 1), dim3(64), 0, stream>>>(Qb, Kb, VT, Ob);
    // out = O @ wo^T (f32)
    gemm_bt<float, false><<<dim3(8, 32, 1), blk, 0, stream>>>(Ob, wb + 3u * 1048576u,
                                                              out, out, out);
}

// Round 9
// 257.725 us; speedup vs baseline: 1.0429x; 1.0429x over previous
//
#include <hip/hip_runtime.h>
#include <stdint.h>

// B=2, T=2048, DIM=1024, H=16, HD=64. Device tensors FLOAT32; internally
// convert to bf16 once, run bf16-MFMA pipeline, final GEMM writes f32.
//
// ws (40MB): xb@0 (8MB), wb@8MB (4x2MB), Kb@16MB [4096,1024],
// VT@24MB [32 bh][64 d][2048 t], Ob@32MB [4096,1024]. Qb (bf16, PRE-SCALED by
// 0.125*log2e) lives in d_out's first 8MB (dead before final GEMM).
//
// GEMM: round-7 single-buffer 128x128 (dbuf regressed: LDS 64KB halved
// blocks/CU and the barrier vmcnt drain is structural — m99/m132).
// attn: swapped QK^T, exp2, defer-max, tree reductions; TWO chains per wave
// on COMPLEMENTARY q-tiles (j, 127-j) so every block does ~34 iteration
// units -> per-CU work is constant under stride-256 dispatch (fixes the 3x
// CU imbalance that held avg occupancy at 12.8%).

#define T_SEQ 2048
#define QSCALE 0.1803368801111204f   // 0.125 * log2(e)

typedef unsigned short u16;
typedef __attribute__((ext_vector_type(8))) __bf16 bf16x8;   // MFMA A/B frag
typedef __attribute__((ext_vector_type(4))) float  f32x4;    // MFMA C/D frag

#define NEG_BIG (-30000.0f)

__device__ __forceinline__ u16 f2bf(float x) {
    union { float f; unsigned u; } c; c.f = x;
    return (u16)((c.u + 0x7fffu + ((c.u >> 16) & 1u)) >> 16);
}

__device__ __forceinline__ void gload_lds16(const void* g, void* l) {
    __builtin_amdgcn_global_load_lds(
        (const __attribute__((address_space(1))) void*)g,
        (__attribute__((address_space(3))) void*)l, 16, 0, 0);
}

__device__ __forceinline__ void storeC(u16* p, float v)   { *p = f2bf(v); }
__device__ __forceinline__ void storeC(float* p, float v) { *p = v; }

// ---------------------------------------------------------------------------
__global__ __launch_bounds__(256) void cvt_all(
    const float* __restrict__ x,  const float* __restrict__ wq,
    const float* __restrict__ wk, const float* __restrict__ wv,
    const float* __restrict__ wo, u16* __restrict__ xb, u16* __restrict__ wb)
{
    int i = blockIdx.x * 256 + threadIdx.x;        // 0 .. 2097151
    const float* s; u16* d; int off;
    if (i < 1048576) { s = x; d = xb; off = i; }
    else {
        int j = i - 1048576;
        int wsel = j >> 18;
        off = j & 262143;
        s = wsel == 0 ? wq : wsel == 1 ? wk : wsel == 2 ? wv : wo;
        d = wb + (size_t)wsel * 1048576u;
    }
    float4 v = ((const float4*)s)[off];
    ushort4 o;
    o.x = f2bf(v.x); o.y = f2bf(v.y); o.z = f2bf(v.z); o.w = f2bf(v.w);
    ((ushort4*)d)[off] = o;
}

// ---------------------------------------------------------------------------
// GEMM: C[4096][1024] = A @ W^T (bf16, both K-contiguous). m97 structure:
// 128x128 tile, BK=64, 4 waves, single-buffer LDS, global_load_lds w=16.
// VT_MODE: z==2 writes C transposed per-head into VT[bh][d][t]; z==0 (Q)
// pre-scales output by QSCALE.
// ---------------------------------------------------------------------------
template <typename OutT, bool VT_MODE>
__global__ __launch_bounds__(256) void gemm_bt(
    const u16* __restrict__ A, const u16* __restrict__ Wb,
    OutT* __restrict__ C0, OutT* __restrict__ C1, OutT* __restrict__ C2)
{
    __shared__ __align__(16) char As[128 * 128];
    __shared__ __align__(16) char Bs[128 * 128];

    const u16* W = Wb + (size_t)blockIdx.z * 1048576u;
    OutT* Cz = blockIdx.z == 0 ? C0 : (blockIdx.z == 1 ? C1 : C2);

    const int tid = threadIdx.x;
    const int w = tid >> 6, l = tid & 63;
    const int wy = w >> 1, wx = w & 1;
    const int bm = blockIdx.y * 128, bn = blockIdx.x * 128;

    f32x4 acc[4][4];
#pragma unroll
    for (int m = 0; m < 4; m++)
#pragma unroll
        for (int n = 0; n < 4; n++) acc[m][n] = (f32x4){0.f, 0.f, 0.f, 0.f};

    const int lrow = l >> 3, lslot = l & 7;

    for (int kt = 0; kt < 16; ++kt) {
#pragma unroll
        for (int c = 0; c < 4; ++c) {
            int ch = w * 4 + c;
            int row = ch * 8 + lrow;
            gload_lds16((const char*)A + ((size_t)(bm + row) * 1024 + kt * 64) * 2 + lslot * 16,
                        As + ch * 1024);
            gload_lds16((const char*)W + ((size_t)(bn + row) * 1024 + kt * 64) * 2 + lslot * 16,
                        Bs + ch * 1024);
        }
        __syncthreads();

#pragma unroll
        for (int kk = 0; kk < 2; ++kk) {
            const int cb = (kk * 32 + (l >> 4) * 8) * 2;
            bf16x8 af[4], bfr[4];
#pragma unroll
            for (int m = 0; m < 4; m++)
                af[m] = *(const bf16x8*)(As + (wy * 64 + m * 16 + (l & 15)) * 128 + cb);
#pragma unroll
            for (int n = 0; n < 4; n++)
                bfr[n] = *(const bf16x8*)(Bs + (wx * 64 + n * 16 + (l & 15)) * 128 + cb);
#pragma unroll
            for (int m = 0; m < 4; m++)
#pragma unroll
                for (int n = 0; n < 4; n++)
                    acc[m][n] = __builtin_amdgcn_mfma_f32_16x16x32_bf16(
                        af[m], bfr[n], acc[m][n], 0, 0, 0);
        }
        __syncthreads();
    }

    const bool vtw = VT_MODE && (blockIdx.z == 2);
    const float osc = (VT_MODE && blockIdx.z == 0) ? QSCALE : 1.0f;
#pragma unroll
    for (int m = 0; m < 4; m++) {
        int grow0 = bm + wy * 64 + m * 16 + (l >> 4) * 4;
#pragma unroll
        for (int n = 0; n < 4; n++) {
            int gcol = bn + wx * 64 + n * 16 + (l & 15);
            if (vtw) {
                int bh = (grow0 >> 11) * 16 + (gcol >> 6);
                size_t rowbase = ((size_t)bh * 64 + (gcol & 63)) * T_SEQ + (grow0 & 2047);
#pragma unroll
                for (int r = 0; r < 4; r++)
                    storeC(&Cz[rowbase + r], acc[m][n][r]);
            } else {
#pragma unroll
                for (int r = 0; r < 4; r++)
                    storeC(&Cz[(size_t)(grow0 + r) * 1024 + gcol], acc[m][n][r] * osc);
            }
        }
    }
}

// ---------------------------------------------------------------------------
// softmax step for one chain (tree reductions, defer-max). Lane owns q-row
// qrow_g; its 16 scores are s[nt][r] at k = kbase + nt*16 + g*4 + r.
// ---------------------------------------------------------------------------
__device__ __forceinline__ void online_sm(
    f32x4 (&s)[4], f32x4 (&oacc)[4], float& mrun, float& lrun,
    int qrow_g, int kbase, bool diag, int g, u16 (*__restrict__ Ps)[72], int q16)
{
    if (diag) {
#pragma unroll
        for (int nt = 0; nt < 4; ++nt)
#pragma unroll
            for (int r = 0; r < 4; ++r)
                if (kbase + nt * 16 + g * 4 + r > qrow_g) s[nt][r] = NEG_BIG;
    }
    float a0 = fmaxf(fmaxf(s[0][0], s[0][1]), fmaxf(s[0][2], s[0][3]));
    float a1 = fmaxf(fmaxf(s[1][0], s[1][1]), fmaxf(s[1][2], s[1][3]));
    float a2 = fmaxf(fmaxf(s[2][0], s[2][1]), fmaxf(s[2][2], s[2][3]));
    float a3 = fmaxf(fmaxf(s[3][0], s[3][1]), fmaxf(s[3][2], s[3][3]));
    float pm = fmaxf(fmaxf(a0, a1), fmaxf(a2, a3));
    pm = fmaxf(pm, __shfl_xor(pm, 16));
    pm = fmaxf(pm, __shfl_xor(pm, 32));

    const bool noresc = __all(pm <= mrun + 8.0f);
    const float mnew = noresc ? mrun : fmaxf(mrun, pm);

#pragma unroll
    for (int nt = 0; nt < 4; ++nt)
#pragma unroll
        for (int r = 0; r < 4; ++r)
            s[nt][r] = __builtin_amdgcn_exp2f(s[nt][r] - mnew);

    float b0 = (s[0][0] + s[0][1]) + (s[0][2] + s[0][3]);
    float b1 = (s[1][0] + s[1][1]) + (s[1][2] + s[1][3]);
    float b2 = (s[2][0] + s[2][1]) + (s[2][2] + s[2][3]);
    float b3 = (s[3][0] + s[3][1]) + (s[3][2] + s[3][3]);
    float rs = (b0 + b1) + (b2 + b3);
    rs += __shfl_xor(rs, 16);
    rs += __shfl_xor(rs, 32);

    if (!noresc) {
        float alpha = __builtin_amdgcn_exp2f(mrun - mnew);
        lrun *= alpha;
#pragma unroll
        for (int nt = 0; nt < 4; ++nt)
#pragma unroll
            for (int r = 0; r < 4; ++r) oacc[nt][r] *= alpha;
        mrun = mnew;
    }
    lrun += rs;

#pragma unroll
    for (int nt = 0; nt < 4; ++nt) {
        ushort4 pk;
        pk.x = f2bf(s[nt][0]); pk.y = f2bf(s[nt][1]);
        pk.z = f2bf(s[nt][2]); pk.w = f2bf(s[nt][3]);
        *(ushort4*)(&Ps[q16][nt * 16 + g * 4]) = pk;
    }
}

// ---------------------------------------------------------------------------
// Flash attention, causal, 1 wave/block. Chain A = q-tile j, chain B =
// q-tile 127-j  ->  per-block work is CONSTANT (~34 iters) so per-CU load
// is balanced for any dispatch order. Shared K/V loads while A is active.
// ---------------------------------------------------------------------------
__global__ __launch_bounds__(64) void attn_fwd(
    const u16* __restrict__ Q, const u16* __restrict__ K,
    const u16* __restrict__ VT, u16* __restrict__ O)
{
    __shared__ __align__(16) u16 PsA[16][72];
    __shared__ __align__(16) u16 PsB[16][72];

    const int bh = blockIdx.x;                     // 0..31
    const int j = blockIdx.y;                      // 0..63
    const int b = bh >> 4, h = bh & 15;
    const int l = threadIdx.x;
    const int g = l >> 4, q16 = l & 15;
    const size_t base = (size_t)b * T_SEQ * 1024 + h * 64;
    const u16* vtb = VT + (size_t)bh * 64 * T_SEQ;

    const int qgA = j * 16, qgB = (127 - j) * 16;
    const int qrA = qgA + q16, qrB = qgB + q16;
    const int ktmaxA = j >> 2, ktmaxB = (127 - j) >> 2;   // ktmaxA < ktmaxB

    const u16* qpA = Q + base + (size_t)qrA * 1024 + g * 8;
    const u16* qpB = Q + base + (size_t)qrB * 1024 + g * 8;
    bf16x8 qfA[2], qfB[2];
    qfA[0] = *(const bf16x8*)(qpA); qfA[1] = *(const bf16x8*)(qpA + 32);
    qfB[0] = *(const bf16x8*)(qpB); qfB[1] = *(const bf16x8*)(qpB + 32);

    f32x4 oaccA[4], oaccB[4];
#pragma unroll
    for (int n = 0; n < 4; n++) {
        oaccA[n] = (f32x4){0.f, 0.f, 0.f, 0.f};
        oaccB[n] = (f32x4){0.f, 0.f, 0.f, 0.f};
    }
    float mA = NEG_BIG, lA = 0.f, mB = NEG_BIG, lB = 0.f;

    bf16x8 kf[2][4], vf[2][4];
    auto load_frags = [&](int kbase) {
#pragma unroll
        for (int kk = 0; kk < 2; ++kk)
#pragma unroll
            for (int nt = 0; nt < 4; ++nt) {
                kf[kk][nt] = *(const bf16x8*)(K + base
                    + (size_t)(kbase + nt * 16 + q16) * 1024 + kk * 32 + g * 8);
                vf[kk][nt] = *(const bf16x8*)(vtb
                    + (size_t)(nt * 16 + q16) * T_SEQ + kbase + kk * 32 + g * 8);
            }
    };

    // ---- phase 1: both chains active (A no-diag), kt in [0, ktmaxA)
    auto iter_both = [&](int kt, bool diagA) {
        const int kbase = kt * 64;
        load_frags(kbase);

        f32x4 sA[4], sB[4];
#pragma unroll
        for (int n = 0; n < 4; n++) {
            sA[n] = (f32x4){0.f, 0.f, 0.f, 0.f};
            sB[n] = (f32x4){0.f, 0.f, 0.f, 0.f};
        }
#pragma unroll
        for (int kk = 0; kk < 2; ++kk)
#pragma unroll
            for (int nt = 0; nt < 4; ++nt) {
                if (!diagA || (kbase + nt * 16 <= qgA + 15))
                    sA[nt] = __builtin_amdgcn_mfma_f32_16x16x32_bf16(
                        kf[kk][nt], qfA[kk], sA[nt], 0, 0, 0);
                sB[nt] = __builtin_amdgcn_mfma_f32_16x16x32_bf16(
                    kf[kk][nt], qfB[kk], sB[nt], 0, 0, 0);
            }

        online_sm(sA, oaccA, mA, lA, qrA, kbase, diagA, g, PsA, q16);
        online_sm(sB, oaccB, mB, lB, qrB, kbase, false, g, PsB, q16);

#pragma unroll
        for (int kk = 0; kk < 2; ++kk) {
            bf16x8 pfA = *(const bf16x8*)(&PsA[q16][kk * 32 + g * 8]);
            bf16x8 pfB = *(const bf16x8*)(&PsB[q16][kk * 32 + g * 8]);
            const bool okA = !diagA || (kbase + kk * 32 <= qgA + 15);
#pragma unroll
            for (int nt = 0; nt < 4; ++nt) {
                if (okA)
                    oaccA[nt] = __builtin_amdgcn_mfma_f32_16x16x32_bf16(
                        vf[kk][nt], pfA, oaccA[nt], 0, 0, 0);
                oaccB[nt] = __builtin_amdgcn_mfma_f32_16x16x32_bf16(
                    vf[kk][nt], pfB, oaccB[nt], 0, 0, 0);
            }
        }
    };

    // ---- phase 2: only chain B
    auto iter_B = [&](int kt, bool diagB) {
        const int kbase = kt * 64;
        load_frags(kbase);

        f32x4 sB[4];
#pragma unroll
        for (int n = 0; n < 4; n++) sB[n] = (f32x4){0.f, 0.f, 0.f, 0.f};
#pragma unroll
        for (int kk = 0; kk < 2; ++kk)
#pragma unroll
            for (int nt = 0; nt < 4; ++nt) {
                if (!diagB || (kbase + nt * 16 <= qgB + 15))
                    sB[nt] = __builtin_amdgcn_mfma_f32_16x16x32_bf16(
                        kf[kk][nt], qfB[kk], sB[nt], 0, 0, 0);
            }

        online_sm(sB, oaccB, mB, lB, qrB, kbase, diagB, g, PsB, q16);

#pragma unroll
        for (int kk = 0; kk < 2; ++kk) {
            bf16x8 pfB = *(const bf16x8*)(&PsB[q16][kk * 32 + g * 8]);
            const bool okB = !diagB || (kbase + kk * 32 <= qgB + 15);
#pragma unroll
            for (int nt = 0; nt < 4; ++nt) {
                if (okB)
                    oaccB[nt] = __builtin_amdgcn_mfma_f32_16x16x32_bf16(
                        vf[kk][nt], pfB, oaccB[nt], 0, 0, 0);
            }
        }
    };

    for (int kt = 0; kt < ktmaxA; ++kt) iter_both(kt, false);
    iter_both(ktmaxA, true);                               // A diagonal
    for (int kt = ktmaxA + 1; kt < ktmaxB; ++kt) iter_B(kt, false);
    iter_B(ktmaxB, true);                                  // B diagonal

    const float riA = __builtin_amdgcn_rcpf(lA);
    const float riB = __builtin_amdgcn_rcpf(lB);
    u16* orowA = O + (size_t)b * T_SEQ * 1024 + (size_t)qrA * 1024 + h * 64;
    u16* orowB = O + (size_t)b * T_SEQ * 1024 + (size_t)qrB * 1024 + h * 64;
#pragma unroll
    for (int nt = 0; nt < 4; ++nt) {
        ushort4 oa, ob;
        oa.x = f2bf(oaccA[nt][0] * riA); oa.y = f2bf(oaccA[nt][1] * riA);
        oa.z = f2bf(oaccA[nt][2] * riA); oa.w = f2bf(oaccA[nt][3] * riA);
        ob.x = f2bf(oaccB[nt][0] * riB); ob.y = f2bf(oaccB[nt][1] * riB);
        ob.z = f2bf(oaccB[nt][2] * riB); ob.w = f2bf(oaccB[nt][3] * riB);
        *(ushort4*)(orowA + nt * 16 + g * 4) = oa;
        *(ushort4*)(orowB + nt * 16 + g * 4) = ob;
    }
}

// ---------------------------------------------------------------------------
extern "C" void kernel_launch(void* const* d_in, const int* in_sizes, int n_in,
                              void* d_out, int out_size, void* d_ws, size_t ws_size,
                              hipStream_t stream)
{
    (void)in_sizes; (void)n_in; (void)out_size; (void)ws_size;
    const float* x  = (const float*)d_in[0];
    const float* wq = (const float*)d_in[1];
    const float* wk = (const float*)d_in[2];
    const float* wv = (const float*)d_in[3];
    const float* wo = (const float*)d_in[4];
    float* out = (float*)d_out;

    char* ws = (char*)d_ws;
    u16* xb = (u16*)(ws);                    // x bf16, 8MB
    u16* wb = (u16*)(ws + (8u << 20));       // wq,wk,wv,wo bf16
    u16* Kb = (u16*)(ws + (16u << 20));      // [4096,1024]
    u16* VT = (u16*)(ws + (24u << 20));      // [32][64][2048] V^T
    u16* Ob = (u16*)(ws + (32u << 20));      // [4096,1024]
    u16* Qb = (u16*)d_out;                   // Q bf16 (pre-scaled) in d_out

    dim3 blk(256);
    cvt_all<<<8192, blk, 0, stream>>>(x, wq, wk, wv, wo, xb, wb);

    // Q (scaled), K row-major; V written transposed into VT
    gemm_bt<u16, true><<<dim3(8, 32, 3), blk, 0, stream>>>(xb, wb, Qb, Kb, VT);
    // causal flash attention: 1-wave blocks, complementary q-tile pairs
    attn_fwd<<<dim3(32, 64, 1), dim3(64), 0, stream>>>(Qb, Kb, VT, Ob);
    // out = O @ wo^T (f32)
    gemm_bt<float, false><<<dim3(8, 32, 1), blk, 0, stream>>>(Ob, wb + 3u * 1048576u,
                                                              out, out, out);
}

// Round 12
// 255.220 us; speedup vs baseline: 1.0531x; 1.0098x over previous
//
#include <hip/hip_runtime.h>
#include <stdint.h>

// B=2, T=2048, DIM=1024, H=16, HD=64. Device tensors FLOAT32; internally
// convert to bf16 once, run bf16-MFMA pipeline, final GEMM writes f32.
//
// ws (40MB): xb@0 (8MB), wb@8MB (4x2MB), Kb@16MB [4096,1024],
// VT@24MB [32 bh][64 d][2048 t], Ob@32MB [4096,1024]. Qb (bf16, PRE-SCALED by
// 0.125*log2e) lives in d_out's first 8MB (dead before final GEMM).
//
// attn v10b (3rd submit; rounds 10/11 were container-level failures):
// identical experiment, pipeline driver rewritten as a counted loop with a
// compile-time bound (was an open-coded for(;;) — removing the only unusual
// control flow in case it interacted with the failures).
// launch_bounds(64,1) lifts the VGPR cap (was 100 -> spills/serial loads);
// 2-deep software pipeline, double-buffered K/V register fragments.
// Two complementary chains (j, 127-j) per wave. Swapped QK^T, in-register
// softmax, exp2 domain, defer-max.

#define T_SEQ 2048
#define QSCALE 0.1803368801111204f   // 0.125 * log2(e)

typedef unsigned short u16;
typedef __attribute__((ext_vector_type(8))) __bf16 bf16x8;   // MFMA A/B frag
typedef __attribute__((ext_vector_type(4))) float  f32x4;    // MFMA C/D frag

#define NEG_BIG (-30000.0f)

__device__ __forceinline__ u16 f2bf(float x) {
    union { float f; unsigned u; } c; c.f = x;
    return (u16)((c.u + 0x7fffu + ((c.u >> 16) & 1u)) >> 16);
}

__device__ __forceinline__ void gload_lds16(const void* g, void* l) {
    __builtin_amdgcn_global_load_lds(
        (const __attribute__((address_space(1))) void*)g,
        (__attribute__((address_space(3))) void*)l, 16, 0, 0);
}

__device__ __forceinline__ void storeC(u16* p, float v)   { *p = f2bf(v); }
__device__ __forceinline__ void storeC(float* p, float v) { *p = v; }

// ---------------------------------------------------------------------------
__global__ __launch_bounds__(256) void cvt_all(
    const float* __restrict__ x,  const float* __restrict__ wq,
    const float* __restrict__ wk, const float* __restrict__ wv,
    const float* __restrict__ wo, u16* __restrict__ xb, u16* __restrict__ wb)
{
    int i = blockIdx.x * 256 + threadIdx.x;        // 0 .. 2097151
    const float* s; u16* d; int off;
    if (i < 1048576) { s = x; d = xb; off = i; }
    else {
        int j = i - 1048576;
        int wsel = j >> 18;
        off = j & 262143;
        s = wsel == 0 ? wq : wsel == 1 ? wk : wsel == 2 ? wv : wo;
        d = wb + (size_t)wsel * 1048576u;
    }
    float4 v = ((const float4*)s)[off];
    ushort4 o;
    o.x = f2bf(v.x); o.y = f2bf(v.y); o.z = f2bf(v.z); o.w = f2bf(v.w);
    ((ushort4*)d)[off] = o;
}

// ---------------------------------------------------------------------------
// GEMM: C[4096][1024] = A @ W^T (bf16, both K-contiguous). m97 structure:
// 128x128 tile, BK=64, 4 waves, single-buffer LDS, global_load_lds w=16.
// VT_MODE: z==2 writes C transposed per-head into VT[bh][d][t]; z==0 (Q)
// pre-scales output by QSCALE.
// ---------------------------------------------------------------------------
template <typename OutT, bool VT_MODE>
__global__ __launch_bounds__(256) void gemm_bt(
    const u16* __restrict__ A, const u16* __restrict__ Wb,
    OutT* __restrict__ C0, OutT* __restrict__ C1, OutT* __restrict__ C2)
{
    __shared__ __align__(16) char As[128 * 128];
    __shared__ __align__(16) char Bs[128 * 128];

    const u16* W = Wb + (size_t)blockIdx.z * 1048576u;
    OutT* Cz = blockIdx.z == 0 ? C0 : (blockIdx.z == 1 ? C1 : C2);

    const int tid = threadIdx.x;
    const int w = tid >> 6, l = tid & 63;
    const int wy = w >> 1, wx = w & 1;
    const int bm = blockIdx.y * 128, bn = blockIdx.x * 128;

    f32x4 acc[4][4];
#pragma unroll
    for (int m = 0; m < 4; m++)
#pragma unroll
        for (int n = 0; n < 4; n++) acc[m][n] = (f32x4){0.f, 0.f, 0.f, 0.f};

    const int lrow = l >> 3, lslot = l & 7;

    for (int kt = 0; kt < 16; ++kt) {
#pragma unroll
        for (int c = 0; c < 4; ++c) {
            int ch = w * 4 + c;
            int row = ch * 8 + lrow;
            gload_lds16((const char*)A + ((size_t)(bm + row) * 1024 + kt * 64) * 2 + lslot * 16,
                        As + ch * 1024);
            gload_lds16((const char*)W + ((size_t)(bn + row) * 1024 + kt * 64) * 2 + lslot * 16,
                        Bs + ch * 1024);
        }
        __syncthreads();

#pragma unroll
        for (int kk = 0; kk < 2; ++kk) {
            const int cb = (kk * 32 + (l >> 4) * 8) * 2;
            bf16x8 af[4], bfr[4];
#pragma unroll
            for (int m = 0; m < 4; m++)
                af[m] = *(const bf16x8*)(As + (wy * 64 + m * 16 + (l & 15)) * 128 + cb);
#pragma unroll
            for (int n = 0; n < 4; n++)
                bfr[n] = *(const bf16x8*)(Bs + (wx * 64 + n * 16 + (l & 15)) * 128 + cb);
#pragma unroll
            for (int m = 0; m < 4; m++)
#pragma unroll
                for (int n = 0; n < 4; n++)
                    acc[m][n] = __builtin_amdgcn_mfma_f32_16x16x32_bf16(
                        af[m], bfr[n], acc[m][n], 0, 0, 0);
        }
        __syncthreads();
    }

    const bool vtw = VT_MODE && (blockIdx.z == 2);
    const float osc = (VT_MODE && blockIdx.z == 0) ? QSCALE : 1.0f;
#pragma unroll
    for (int m = 0; m < 4; m++) {
        int grow0 = bm + wy * 64 + m * 16 + (l >> 4) * 4;
#pragma unroll
        for (int n = 0; n < 4; n++) {
            int gcol = bn + wx * 64 + n * 16 + (l & 15);
            if (vtw) {
                int bh = (grow0 >> 11) * 16 + (gcol >> 6);
                size_t rowbase = ((size_t)bh * 64 + (gcol & 63)) * T_SEQ + (grow0 & 2047);
#pragma unroll
                for (int r = 0; r < 4; r++)
                    storeC(&Cz[rowbase + r], acc[m][n][r]);
            } else {
#pragma unroll
                for (int r = 0; r < 4; r++)
                    storeC(&Cz[(size_t)(grow0 + r) * 1024 + gcol], acc[m][n][r] * osc);
            }
        }
    }
}

// ---------------------------------------------------------------------------
// softmax step for one chain (tree reductions, defer-max). Lane owns q-row
// qrow_g; its 16 scores are s[nt][r] at k = kbase + nt*16 + g*4 + r.
// ---------------------------------------------------------------------------
__device__ __forceinline__ void online_sm(
    f32x4 (&s)[4], f32x4 (&oacc)[4], float& mrun, float& lrun,
    int qrow_g, int kbase, bool diag, int g, u16 (*__restrict__ Ps)[72], int q16)
{
    if (diag) {
#pragma unroll
        for (int nt = 0; nt < 4; ++nt)
#pragma unroll
            for (int r = 0; r < 4; ++r)
                if (kbase + nt * 16 + g * 4 + r > qrow_g) s[nt][r] = NEG_BIG;
    }
    float a0 = fmaxf(fmaxf(s[0][0], s[0][1]), fmaxf(s[0][2], s[0][3]));
    float a1 = fmaxf(fmaxf(s[1][0], s[1][1]), fmaxf(s[1][2], s[1][3]));
    float a2 = fmaxf(fmaxf(s[2][0], s[2][1]), fmaxf(s[2][2], s[2][3]));
    float a3 = fmaxf(fmaxf(s[3][0], s[3][1]), fmaxf(s[3][2], s[3][3]));
    float pm = fmaxf(fmaxf(a0, a1), fmaxf(a2, a3));
    pm = fmaxf(pm, __shfl_xor(pm, 16));
    pm = fmaxf(pm, __shfl_xor(pm, 32));

    const bool noresc = __all(pm <= mrun + 8.0f);
    const float mnew = noresc ? mrun : fmaxf(mrun, pm);

#pragma unroll
    for (int nt = 0; nt < 4; ++nt)
#pragma unroll
        for (int r = 0; r < 4; ++r)
            s[nt][r] = __builtin_amdgcn_exp2f(s[nt][r] - mnew);

    float b0 = (s[0][0] + s[0][1]) + (s[0][2] + s[0][3]);
    float b1 = (s[1][0] + s[1][1]) + (s[1][2] + s[1][3]);
    float b2 = (s[2][0] + s[2][1]) + (s[2][2] + s[2][3]);
    float b3 = (s[3][0] + s[3][1]) + (s[3][2] + s[3][3]);
    float rs = (b0 + b1) + (b2 + b3);
    rs += __shfl_xor(rs, 16);
    rs += __shfl_xor(rs, 32);

    if (!noresc) {
        float alpha = __builtin_amdgcn_exp2f(mrun - mnew);
        lrun *= alpha;
#pragma unroll
        for (int nt = 0; nt < 4; ++nt)
#pragma unroll
            for (int r = 0; r < 4; ++r) oacc[nt][r] *= alpha;
        mrun = mnew;
    }
    lrun += rs;

#pragma unroll
    for (int nt = 0; nt < 4; ++nt) {
        ushort4 pk;
        pk.x = f2bf(s[nt][0]); pk.y = f2bf(s[nt][1]);
        pk.z = f2bf(s[nt][2]); pk.w = f2bf(s[nt][3]);
        *(ushort4*)(&Ps[q16][nt * 16 + g * 4]) = pk;
    }
}

// ---------------------------------------------------------------------------
// Flash attention, causal, 1 wave/block. Chain A = q-tile j, chain B =
// q-tile 127-j (constant per-block work). 2-deep software pipeline:
// double-buffered K/V register fragments, prefetch kt+1 before computing kt.
// Driver is a counted loop (trip count <= 17), all buffer indices static.
// ---------------------------------------------------------------------------
__global__ __launch_bounds__(64, 1) void attn_fwd(
    const u16* __restrict__ Q, const u16* __restrict__ K,
    const u16* __restrict__ VT, u16* __restrict__ O)
{
    __shared__ __align__(16) u16 PsA[16][72];
    __shared__ __align__(16) u16 PsB[16][72];

    const int bh = blockIdx.x;                     // 0..31
    const int j = blockIdx.y;                      // 0..63
    const int b = bh >> 4, h = bh & 15;
    const int l = threadIdx.x;
    const int g = l >> 4, q16 = l & 15;
    const size_t base = (size_t)b * T_SEQ * 1024 + h * 64;
    const u16* vtb = VT + (size_t)bh * 64 * T_SEQ;

    const int qgA = j * 16, qgB = (127 - j) * 16;
    const int qrA = qgA + q16, qrB = qgB + q16;
    const int ktA = j >> 2, ktB = (127 - j) >> 2;  // 0 <= ktA < ktB <= 31

    const u16* qpA = Q + base + (size_t)qrA * 1024 + g * 8;
    const u16* qpB = Q + base + (size_t)qrB * 1024 + g * 8;
    bf16x8 qfA[2], qfB[2];
    qfA[0] = *(const bf16x8*)(qpA); qfA[1] = *(const bf16x8*)(qpA + 32);
    qfB[0] = *(const bf16x8*)(qpB); qfB[1] = *(const bf16x8*)(qpB + 32);

    f32x4 oaccA[4], oaccB[4];
#pragma unroll
    for (int n = 0; n < 4; n++) {
        oaccA[n] = (f32x4){0.f, 0.f, 0.f, 0.f};
        oaccB[n] = (f32x4){0.f, 0.f, 0.f, 0.f};
    }
    float mA = NEG_BIG, lA = 0.f, mB = NEG_BIG, lB = 0.f;

    bf16x8 kfa[2][4], vfa[2][4], kfb[2][4], vfb[2][4];   // double-buffered frags

    auto lf = [&](int kbase, bf16x8 (&kf)[2][4], bf16x8 (&vf)[2][4]) {
#pragma unroll
        for (int kk = 0; kk < 2; ++kk)
#pragma unroll
            for (int nt = 0; nt < 4; ++nt) {
                kf[kk][nt] = *(const bf16x8*)(K + base
                    + (size_t)(kbase + nt * 16 + q16) * 1024 + kk * 32 + g * 8);
                vf[kk][nt] = *(const bf16x8*)(vtb
                    + (size_t)(nt * 16 + q16) * T_SEQ + kbase + kk * 32 + g * 8);
            }
    };

    auto body = [&](int t, bf16x8 (&kf)[2][4], bf16x8 (&vf)[2][4]) {
        const int kbase = t * 64;
        const bool actA = (t <= ktA);
        const bool dA = (t == ktA), dB = (t == ktB);

        f32x4 sA[4], sB[4];
#pragma unroll
        for (int n = 0; n < 4; n++) {
            sA[n] = (f32x4){0.f, 0.f, 0.f, 0.f};
            sB[n] = (f32x4){0.f, 0.f, 0.f, 0.f};
        }
        if (actA) {
#pragma unroll
            for (int kk = 0; kk < 2; ++kk)
#pragma unroll
                for (int nt = 0; nt < 4; ++nt)
                    sA[nt] = __builtin_amdgcn_mfma_f32_16x16x32_bf16(
                        kf[kk][nt], qfA[kk], sA[nt], 0, 0, 0);
        }
#pragma unroll
        for (int kk = 0; kk < 2; ++kk)
#pragma unroll
            for (int nt = 0; nt < 4; ++nt)
                sB[nt] = __builtin_amdgcn_mfma_f32_16x16x32_bf16(
                    kf[kk][nt], qfB[kk], sB[nt], 0, 0, 0);

        if (actA) online_sm(sA, oaccA, mA, lA, qrA, kbase, dA, g, PsA, q16);
        online_sm(sB, oaccB, mB, lB, qrB, kbase, dB, g, PsB, q16);

#pragma unroll
        for (int kk = 0; kk < 2; ++kk) {
            bf16x8 pfB = *(const bf16x8*)(&PsB[q16][kk * 32 + g * 8]);
#pragma unroll
            for (int nt = 0; nt < 4; ++nt)
                oaccB[nt] = __builtin_amdgcn_mfma_f32_16x16x32_bf16(
                    vf[kk][nt], pfB, oaccB[nt], 0, 0, 0);
        }
        if (actA) {
#pragma unroll
            for (int kk = 0; kk < 2; ++kk) {
                bf16x8 pfA = *(const bf16x8*)(&PsA[q16][kk * 32 + g * 8]);
#pragma unroll
                for (int nt = 0; nt < 4; ++nt)
                    oaccA[nt] = __builtin_amdgcn_mfma_f32_16x16x32_bf16(
                        vf[kk][nt], pfA, oaccA[nt], 0, 0, 0);
            }
        }
    };

    // ---- pipelined driver: counted loop, trip count bounded by 17,
    //      all register-buffer indices compile-time static.
    lf(0, kfa, vfa);
    const int npair = (ktB + 2) >> 1;              // pairs of (even,odd) steps
    for (int p = 0; p < npair; ++p) {
        const int t0 = 2 * p, t1 = 2 * p + 1;
        if (t0 < ktB) lf((t0 + 1) * 64, kfb, vfb);
        body(t0, kfa, vfa);
        if (t1 <= ktB) {
            if (t1 < ktB) lf((t1 + 1) * 64, kfa, vfa);
            body(t1, kfb, vfb);
        }
    }

    // ---- epilogue
    const float riA = __builtin_amdgcn_rcpf(lA);
    const float riB = __builtin_amdgcn_rcpf(lB);
    u16* orowA = O + (size_t)b * T_SEQ * 1024 + (size_t)qrA * 1024 + h * 64;
    u16* orowB = O + (size_t)b * T_SEQ * 1024 + (size_t)qrB * 1024 + h * 64;
#pragma unroll
    for (int nt = 0; nt < 4; ++nt) {
        ushort4 oa, ob;
        oa.x = f2bf(oaccA[nt][0] * riA); oa.y = f2bf(oaccA[nt][1] * riA);
        oa.z = f2bf(oaccA[nt][2] * riA); oa.w = f2bf(oaccA[nt][3] * riA);
        ob.x = f2bf(oaccB[nt][0] * riB); ob.y = f2bf(oaccB[nt][1] * riB);
        ob.z = f2bf(oaccB[nt][2] * riB); ob.w = f2bf(oaccB[nt][3] * riB);
        *(ushort4*)(orowA + nt * 16 + g * 4) = oa;
        *(ushort4*)(orowB + nt * 16 + g * 4) = ob;
    }
}

// ---------------------------------------------------------------------------
extern "C" void kernel_launch(void* const* d_in, const int* in_sizes, int n_in,
                              void* d_out, int out_size, void* d_ws, size_t ws_size,
                              hipStream_t stream)
{
    (void)in_sizes; (void)n_in; (void)out_size; (void)ws_size;
    const float* x  = (const float*)d_in[0];
    const float* wq = (const float*)d_in[1];
    const float* wk = (const float*)d_in[2];
    const float* wv = (const float*)d_in[3];
    const float* wo = (const float*)d_in[4];
    float* out = (float*)d_out;

    char* ws = (char*)d_ws;
    u16* xb = (u16*)(ws);                    // x bf16, 8MB
    u16* wb = (u16*)(ws + (8u << 20));       // wq,wk,wv,wo bf16
    u16* Kb = (u16*)(ws + (16u << 20));      // [4096,1024]
    u16* VT = (u16*)(ws + (24u << 20));      // [32][64][2048] V^T
    u16* Ob = (u16*)(ws + (32u << 20));      // [4096,1024]
    u16* Qb = (u16*)d_out;                   // Q bf16 (pre-scaled) in d_out

    dim3 blk(256);
    cvt_all<<<8192, blk, 0, stream>>>(x, wq, wk, wv, wo, xb, wb);

    // Q (scaled), K row-major; V written transposed into VT
    gemm_bt<u16, true><<<dim3(8, 32, 3), blk, 0, stream>>>(xb, wb, Qb, Kb, VT);
    // causal flash attention: 1-wave blocks, complementary q-tile pairs
    attn_fwd<<<dim3(32, 64, 1), dim3(64), 0, stream>>>(Qb, Kb, VT, Ob);
    // out = O @ wo^T (f32)
    gemm_bt<float, false><<<dim3(8, 32, 1), blk, 0, stream>>>(Ob, wb + 3u * 1048576u,
                                                              out, out, out);
}